// Round 3
// baseline (107.469 us; speedup 1.0000x reference)
//
#include <hip/hip_runtime.h>

constexpr int Bn = 1024;
constexpr int Dn = 64;
constexpr int Cn = 100000;
constexpr int Kn = 5;
constexpr float LOG2E = 1.44269504088896f;
constexpr float LN2   = 0.69314718055994531f;

typedef float f32x4  __attribute__((ext_vector_type(4)));
typedef short bf16x8 __attribute__((ext_vector_type(8)));

__device__ __forceinline__ unsigned short f32_to_bf16(float f) {
  union { float f; unsigned int u; } v; v.f = f;
  unsigned int r = v.u + 0x7FFFu + ((v.u >> 16) & 1u);  // RNE
  return (unsigned short)(r >> 16);
}
__device__ __forceinline__ float bf16_to_f32(unsigned short u) {
  union { unsigned int i; float f; } v; v.i = ((unsigned int)u) << 16; return v.f;
}

// ===================== FUSED PATH =====================
constexpr int SPLITS = 125;          // class splits, 800 classes each (exact)
constexpr int CPS    = Cn / SPLITS;  // 800
constexpr int NCH    = CPS / 32;     // 25 chunks of 32 classes
constexpr int GRID   = SPLITS * 4;   // 500 blocks, XCD-chunked mapping

__device__ __forceinline__ void loadChunk(
    const unsigned short* __restrict__ Wt, const float* __restrict__ bias,
    int cb, int lr, int lg, bf16x8 (&b)[2][2], float (&bb)[2])
{
  const unsigned short* p0 = Wt + (size_t)(cb + lr) * 64 + lg * 8;
  const unsigned short* p1 = p0 + 16 * 64;
  b[0][0] = *reinterpret_cast<const bf16x8*>(p0);
  b[0][1] = *reinterpret_cast<const bf16x8*>(p0 + 32);
  b[1][0] = *reinterpret_cast<const bf16x8*>(p1);
  b[1][1] = *reinterpret_cast<const bf16x8*>(p1 + 32);
  bb[0] = bias[cb + lr] * LOG2E;
  bb[1] = bias[cb + 16 + lr] * LOG2E;
}

// A pre-scaled by LOG2E; bias*LOG2E is the MFMA C-init -> exp2 of raw acc.
__device__ __forceinline__ void computeChunk(
    const bf16x8 (&a)[4][2], const bf16x8 (&b)[2][2], const float (&bb)[2],
    float (&esum)[4][4])
{
  f32x4 acc[4][2];
#pragma unroll
  for (int t = 0; t < 4; ++t) {
    acc[t][0] = f32x4{bb[0], bb[0], bb[0], bb[0]};
    acc[t][1] = f32x4{bb[1], bb[1], bb[1], bb[1]};
  }
#pragma unroll
  for (int t = 0; t < 4; ++t) {
    acc[t][0] = __builtin_amdgcn_mfma_f32_16x16x32_bf16(a[t][0], b[0][0], acc[t][0], 0, 0, 0);
    acc[t][1] = __builtin_amdgcn_mfma_f32_16x16x32_bf16(a[t][0], b[1][0], acc[t][1], 0, 0, 0);
    acc[t][0] = __builtin_amdgcn_mfma_f32_16x16x32_bf16(a[t][1], b[0][1], acc[t][0], 0, 0, 0);
    acc[t][1] = __builtin_amdgcn_mfma_f32_16x16x32_bf16(a[t][1], b[1][1], acc[t][1], 0, 0, 0);
  }
#pragma unroll
  for (int t = 0; t < 4; ++t)
#pragma unroll
    for (int j = 0; j < 4; ++j) {
      const float e0 = __builtin_amdgcn_exp2f(acc[t][0][j]);
      const float e1 = __builtin_amdgcn_exp2f(acc[t][1][j]);
      esum[t][j] += e0 + e1;
    }
}

// One kernel: per-block COALESCED W-slice conversion (LDS tile transpose, the
// proven prep pattern) into global Wt (L2-resident, own XCD), then the
// streaming MFMA+exp loop. Each block only reads Wt bytes it wrote itself.
__global__ __launch_bounds__(256) void fused_gemm_kernel(
    const float* __restrict__ x, const float* __restrict__ W,
    const float* __restrict__ bias, unsigned short* __restrict__ Wt,
    float* __restrict__ P, float* __restrict__ out)
{
  __shared__ unsigned short tmp[64][165];   // 5 tiles x [64 d][33-pad c] bf16

  const int b   = blockIdx.x;
  const int tid = threadIdx.x;
  if (b == 0 && tid == 0) *out = 0.f;

  // Bijective chunked XCD mapping (nwg=500: q=62, r=4): consecutive wgid ->
  // same XCD, so a split's 4 sgrp blocks share L2 for the duplicated W reads.
  const int xcd = b & 7, bs = b >> 3;
  const int wgid = (xcd < 4 ? xcd * 63 : 252 + (xcd - 4) * 62) + bs;
  const int split = wgid >> 2, sgrp = wgid & 3;

  const int lane = tid & 63, wid = tid >> 6;
  const int lr = lane & 15, lg = lane >> 4;
  const int sbase = sgrp * 256 + wid * 64;
  const int cb0   = split * CPS;

  // ---- Prologue A: x f32 -> A-frags in registers, scaled by LOG2E.
  bf16x8 a[4][2];
#pragma unroll
  for (int t = 0; t < 4; ++t) {
    const float* xp = x + (size_t)(sbase + t * 16 + lr) * 64 + lg * 8;
    const float4 v0 = *reinterpret_cast<const float4*>(xp);
    const float4 v1 = *reinterpret_cast<const float4*>(xp + 4);
    const float4 v2 = *reinterpret_cast<const float4*>(xp + 32);
    const float4 v3 = *reinterpret_cast<const float4*>(xp + 36);
    bf16x8 a0, a1;
    a0[0] = (short)f32_to_bf16(v0.x * LOG2E);
    a0[1] = (short)f32_to_bf16(v0.y * LOG2E);
    a0[2] = (short)f32_to_bf16(v0.z * LOG2E);
    a0[3] = (short)f32_to_bf16(v0.w * LOG2E);
    a0[4] = (short)f32_to_bf16(v1.x * LOG2E);
    a0[5] = (short)f32_to_bf16(v1.y * LOG2E);
    a0[6] = (short)f32_to_bf16(v1.z * LOG2E);
    a0[7] = (short)f32_to_bf16(v1.w * LOG2E);
    a1[0] = (short)f32_to_bf16(v2.x * LOG2E);
    a1[1] = (short)f32_to_bf16(v2.y * LOG2E);
    a1[2] = (short)f32_to_bf16(v2.z * LOG2E);
    a1[3] = (short)f32_to_bf16(v2.w * LOG2E);
    a1[4] = (short)f32_to_bf16(v3.x * LOG2E);
    a1[5] = (short)f32_to_bf16(v3.y * LOG2E);
    a1[6] = (short)f32_to_bf16(v3.z * LOG2E);
    a1[7] = (short)f32_to_bf16(v3.w * LOG2E);
    a[t][0] = a0;
    a[t][1] = a1;
  }

  // ---- Prologue B: W[64][split-slice] f32 -> Wt[c][64] bf16, COALESCED.
  // 5 rounds x 5 tiles of 32 classes; LDS tile transpose (prep's pattern).
  {
    const int c   = tid & 31, dq  = tid >> 5;   // load roles
    const int cl  = tid >> 3, oct = tid & 7;    // transpose roles
#pragma unroll 1
    for (int r = 0; r < 5; ++r) {
      const int cbase = cb0 + r * 160;
#pragma unroll
      for (int s = 0; s < 5; ++s)
#pragma unroll
        for (int j = 0; j < 8; ++j) {
          const int d = dq * 8 + j;
          tmp[d][s * 33 + c] =
              f32_to_bf16(W[(size_t)d * Cn + (cbase + s * 32 + c)]);
        }
      __syncthreads();
#pragma unroll
      for (int s = 0; s < 5; ++s) {
        bf16x8 o;
#pragma unroll
        for (int j = 0; j < 8; ++j) o[j] = (short)tmp[oct * 8 + j][s * 33 + cl];
        *reinterpret_cast<bf16x8*>(
            Wt + (size_t)(cbase + s * 32 + cl) * 64 + oct * 8) = o;
      }
      __syncthreads();   // also drains vmem: our Wt writes are L2-visible
    }
  }

  // ---- Main loop: stream 25 chunks of 32 classes from (L2-hot) Wt.
  float esum[4][4];
#pragma unroll
  for (int t = 0; t < 4; ++t)
#pragma unroll
    for (int j = 0; j < 4; ++j) esum[t][j] = 0.f;

  bf16x8 bX[2][2]; float bbX[2];
  bf16x8 bY[2][2]; float bbY[2];
  loadChunk(Wt, bias, cb0, lr, lg, bX, bbX);
#pragma unroll 1
  for (int ch = 0; ch < NCH; ch += 2) {
    if (ch + 1 < NCH) loadChunk(Wt, bias, cb0 + (ch + 1) * 32, lr, lg, bY, bbY);
    computeChunk(a, bX, bbX, esum);
    if (ch + 1 < NCH) {
      if (ch + 2 < NCH) loadChunk(Wt, bias, cb0 + (ch + 2) * 32, lr, lg, bX, bbX);
      computeChunk(a, bY, bbY, esum);
    }
  }

  // Reduce over the 16 lr-lanes (classes), once.
  float red[4][4];
#pragma unroll
  for (int t = 0; t < 4; ++t)
#pragma unroll
    for (int j = 0; j < 4; ++j) {
      float v = esum[t][j];
      v += __shfl_xor(v, 1, 64);
      v += __shfl_xor(v, 2, 64);
      v += __shfl_xor(v, 4, 64);
      v += __shfl_xor(v, 8, 64);
      red[t][j] = v;
    }
  if (lr == 0) {
#pragma unroll
    for (int t = 0; t < 4; ++t)
#pragma unroll
      for (int j = 0; j < 4; ++j)
        P[(size_t)(sbase + t * 16 + lg * 4 + j) * SPLITS + split] = red[t][j];
  }
}

// Loss: reduce P over splits (coalesced) + positives recomputed in the same
// log2 domain with bit-identical bf16 rounding of x and W.
__global__ __launch_bounds__(64) void loss2_kernel(
    const float* __restrict__ x, const int* __restrict__ labels,
    const unsigned short* __restrict__ Wt, const float* __restrict__ bias,
    const float* __restrict__ P, float* __restrict__ out)
{
  const int i = blockIdx.x, lane = threadIdx.x;
  float acc = P[(size_t)i * SPLITS + lane];
  if (lane + 64 < SPLITS) acc += P[(size_t)i * SPLITS + lane + 64];
#pragma unroll
  for (int off = 32; off > 0; off >>= 1) acc += __shfl_xor(acc, off, 64);
  const float Si = acc;

  const float xv = bf16_to_f32(f32_to_bf16(x[i * Dn + lane] * LOG2E));  // == A-frag value
  float l2[Kn];
#pragma unroll
  for (int p = 0; p < Kn; ++p) {
    const int c = labels[i * Kn + p];
    float v = xv * bf16_to_f32(Wt[(size_t)c * 64 + lane]);
#pragma unroll
    for (int off = 32; off > 0; off >>= 1) v += __shfl_xor(v, off, 64);
    l2[p] = v + bias[c] * LOG2E;    // logit * LOG2E
  }
  if (lane == 0) {
    float Psum = 0.f;
#pragma unroll
    for (int p = 0; p < Kn; ++p) Psum += __builtin_amdgcn_exp2f(l2[p]);
    const float neg = Si - Psum;
    float lsum = 0.f;
#pragma unroll
    for (int p = 0; p < Kn; ++p)
      lsum += __logf(__builtin_amdgcn_exp2f(l2[p]) + neg) - l2[p] * LN2;
    atomicAdd(out, lsum * (1.0f / (float)(Bn * Kn)));
  }
}

// ===================== OLD (round-2) FALLBACK PATH =====================
constexpr int NB  = 128;
constexpr int NPB = (Cn + NB - 1) / NB;
constexpr int NPBpad = 784;

__global__ __launch_bounds__(256) void cvt_x_kernel(
    const float* __restrict__ x, unsigned short* __restrict__ xb)
{
  const int i = (blockIdx.x * 256 + threadIdx.x) * 4;
  const float4 v = *reinterpret_cast<const float4*>(x + i);
  ushort4 o;
  o.x = f32_to_bf16(v.x); o.y = f32_to_bf16(v.y);
  o.z = f32_to_bf16(v.z); o.w = f32_to_bf16(v.w);
  *reinterpret_cast<ushort4*>(xb + i) = o;
}

__global__ __launch_bounds__(256) void expsum_mfma_kernel(
    const unsigned short* __restrict__ xb, const float* __restrict__ W,
    const float* __restrict__ bias, float* __restrict__ P,
    float* __restrict__ S, int use_partials)
{
  __shared__ float S_lds[4][Bn];
  const int tid  = threadIdx.x;
  const int lane = tid & 63, wid = tid >> 6;
  const int lg = lane >> 4, lr = lane & 15;
  const int cbase = blockIdx.x * NB + wid * 32;

  for (int i = tid; i < 4 * Bn; i += 256) (&S_lds[0][0])[i] = 0.f;

  bf16x8 bfrag[2][2];
  float  bval[2];
#pragma unroll
  for (int t = 0; t < 2; ++t) {
    const int c  = cbase + t * 16 + lr;
    const bool ok = (c < Cn);
    bval[t] = ok ? bias[c] * LOG2E : -1e38f;
#pragma unroll
    for (int h = 0; h < 2; ++h) {
      bf16x8 bf;
#pragma unroll
      for (int j = 0; j < 8; ++j) {
        const int d = h * 32 + lg * 8 + j;
        const float w = ok ? W[(size_t)d * Cn + c] : 0.f;
        bf[j] = (short)f32_to_bf16(w);
      }
      bfrag[t][h] = bf;
    }
  }
  __syncthreads();

#pragma unroll 1
  for (int ch = 0; ch < Bn / 16; ++ch) {
    const int s = ch * 16 + lr;
    const bf16x8 a0 = *reinterpret_cast<const bf16x8*>(xb + (size_t)s * Dn + lg * 8);
    const bf16x8 a1 = *reinterpret_cast<const bf16x8*>(xb + (size_t)s * Dn + 32 + lg * 8);
    f32x4 acc0 = {0.f, 0.f, 0.f, 0.f};
    f32x4 acc1 = {0.f, 0.f, 0.f, 0.f};
    acc0 = __builtin_amdgcn_mfma_f32_16x16x32_bf16(a0, bfrag[0][0], acc0, 0, 0, 0);
    acc1 = __builtin_amdgcn_mfma_f32_16x16x32_bf16(a0, bfrag[1][0], acc1, 0, 0, 0);
    acc0 = __builtin_amdgcn_mfma_f32_16x16x32_bf16(a1, bfrag[0][1], acc0, 0, 0, 0);
    acc1 = __builtin_amdgcn_mfma_f32_16x16x32_bf16(a1, bfrag[1][1], acc1, 0, 0, 0);

    float v[4];
#pragma unroll
    for (int j = 0; j < 4; ++j) {
      const float e0 = __builtin_amdgcn_exp2f(fmaf(acc0[j], LOG2E, bval[0]));
      const float e1 = __builtin_amdgcn_exp2f(fmaf(acc1[j], LOG2E, bval[1]));
      v[j] = e0 + e1;
    }
#pragma unroll
    for (int j = 0; j < 4; ++j) {
      v[j] += __shfl_xor(v[j], 1, 64);
      v[j] += __shfl_xor(v[j], 2, 64);
      v[j] += __shfl_xor(v[j], 4, 64);
      v[j] += __shfl_xor(v[j], 8, 64);
    }
    if (lr == 0) {
#pragma unroll
      for (int j = 0; j < 4; ++j)
        S_lds[wid][ch * 16 + lg * 4 + j] += v[j];
    }
  }
  __syncthreads();

  if (use_partials) {
    for (int s2 = tid; s2 < Bn; s2 += 256) {
      const float v = S_lds[0][s2] + S_lds[1][s2] + S_lds[2][s2] + S_lds[3][s2];
      P[(size_t)s2 * NPBpad + blockIdx.x] = v;
    }
  } else {
    for (int s2 = tid; s2 < Bn; s2 += 256) {
      const float v = S_lds[0][s2] + S_lds[1][s2] + S_lds[2][s2] + S_lds[3][s2];
      atomicAdd(&S[s2], v);
    }
  }
}

__global__ __launch_bounds__(64) void loss_kernel(
    const float* __restrict__ x, const int* __restrict__ labels,
    const float* __restrict__ W, const float* __restrict__ bias,
    const float* __restrict__ P, const float* __restrict__ S,
    float* __restrict__ out, int use_partials)
{
  const int i    = blockIdx.x;
  const int lane = threadIdx.x;

  float Si;
  if (use_partials) {
    float acc = 0.f;
    for (int j = lane; j < NPB; j += 64) acc += P[(size_t)i * NPBpad + j];
#pragma unroll
    for (int off = 32; off > 0; off >>= 1) acc += __shfl_xor(acc, off, 64);
    Si = acc;
  } else {
    Si = S[i];
  }

  const float xv = x[i * Dn + lane];
  float l[Kn];
#pragma unroll
  for (int p = 0; p < Kn; ++p) {
    const int c = labels[i * Kn + p];
    float v = xv * W[(size_t)lane * Cn + c];
#pragma unroll
    for (int off = 32; off > 0; off >>= 1) v += __shfl_xor(v, off, 64);
    l[p] = v + bias[c];
  }

  if (lane == 0) {
    float Psum = 0.f;
#pragma unroll
    for (int p = 0; p < Kn; ++p) Psum += __expf(l[p]);
    const float neg = Si - Psum;
    float lsum = 0.f;
#pragma unroll
    for (int p = 0; p < Kn; ++p)
      lsum += __logf(__expf(l[p]) + neg) - l[p];
    atomicAdd(out, lsum * (1.0f / (float)(Bn * Kn)));
  }
}

// ===================== launch =====================
extern "C" void kernel_launch(void* const* d_in, const int* in_sizes, int n_in,
                              void* d_out, int out_size, void* d_ws, size_t ws_size,
                              hipStream_t stream) {
  const float* x      = (const float*)d_in[0];
  const int*   labels = (const int*)d_in[1];
  const float* W      = (const float*)d_in[2];
  const float* bias   = (const float*)d_in[3];
  float*       out    = (float*)d_out;
  char*        ws     = (char*)d_ws;

  // Fused-path ws layout: P[512000) | Wt[12.8M)
  const size_t off_P  = 0;
  const size_t off_Wt = (size_t)SPLITS * Bn * 4;             // 512000
  const size_t need_new = off_Wt + (size_t)Cn * Dn * 2;      // 13312000

  if (ws_size >= need_new) {
    float*          P  = (float*)(ws + off_P);
    unsigned short* Wt = (unsigned short*)(ws + off_Wt);
    fused_gemm_kernel<<<GRID, 256, 0, stream>>>(x, W, bias, Wt, P, out);
    loss2_kernel<<<Bn, 64, 0, stream>>>(x, labels, Wt, bias, P, out);
    return;
  }

  // Fallback: round-2 path.
  hipMemsetAsync(out, 0, sizeof(float), stream);
  float*          Sg = (float*)ws;
  unsigned short* xb = (unsigned short*)(ws + 4096);
  float*          Pp = (float*)(ws + 4096 + (size_t)Bn * Dn * 2);
  const size_t need_old = 4096 + (size_t)Bn * Dn * 2 + (size_t)Bn * NPBpad * 4;
  const int use_partials = (ws_size >= need_old) ? 1 : 0;
  if (!use_partials) hipMemsetAsync(Sg, 0, Bn * sizeof(float), stream);

  cvt_x_kernel<<<(Bn * Dn) / (256 * 4), 256, 0, stream>>>(x, xb);
  expsum_mfma_kernel<<<NPB, 256, 0, stream>>>(xb, W, bias, Pp, Sg, use_partials);
  loss_kernel<<<Bn, 64, 0, stream>>>(x, labels, W, bias, Pp, Sg, out, use_partials);
}

// Round 4
// 70.847 us; speedup vs baseline: 1.5169x; 1.5169x over previous
//
#include <hip/hip_runtime.h>

constexpr int Bn = 1024;
constexpr int Dn = 64;
constexpr int Cn = 100000;
constexpr int Kn = 5;
constexpr float LOG2E = 1.44269504088896f;
constexpr float LN2   = 0.69314718055994531f;

typedef float f32x4  __attribute__((ext_vector_type(4)));
typedef short bf16x8 __attribute__((ext_vector_type(8)));

__device__ __forceinline__ unsigned short f32_to_bf16(float f) {
  union { float f; unsigned int u; } v; v.f = f;
  unsigned int r = v.u + 0x7FFFu + ((v.u >> 16) & 1u);  // RNE
  return (unsigned short)(r >> 16);
}
__device__ __forceinline__ float bf16_to_f32(unsigned short u) {
  union { unsigned int i; float f; } v; v.i = ((unsigned int)u) << 16; return v.f;
}

// ===================== MAIN PATH (round-1 structure) =====================
// SPLITS=625 for occupancy: 2500 gemm blocks ~= 8 waves/SIMD (was 2).
constexpr int SPLITS = 625;          // class splits, 160 classes each (exact)
constexpr int CPS    = Cn / SPLITS;  // 160
constexpr int NCH    = CPS / 32;     // 5 chunks of 32 classes
constexpr int GRID   = SPLITS * 4;   // 2500 blocks
constexpr int NBLK_W = (Cn + 63) / 64;   // 1563 transpose tiles

// Prep: W[64][C] f32 -> Wt[C][64] bf16 (class-major), x -> bf16(x*LOG2E),
// and zero out. Proven coalesced LDS-tile transpose (round-1).
__global__ __launch_bounds__(256) void prep_kernel(
    const float* __restrict__ x, const float* __restrict__ W,
    unsigned short* __restrict__ xb, unsigned short* __restrict__ Wt,
    float* __restrict__ out)
{
  const int tid = threadIdx.x;
  const int b   = blockIdx.x;
  if (b == 0 && tid == 0) *out = 0.f;   // replaces hipMemsetAsync dispatch
  if (b < NBLK_W) {
    __shared__ unsigned short tile[64][71];   // [d][c]; odd pad
    const int c0   = b * 64;
    const int cIdx = tid & 63, dIdx = tid >> 6;
#pragma unroll
    for (int k = 0; k < 16; ++k) {
      const int d = dIdx * 16 + k;
      const int c = c0 + cIdx;
      const float v = (c < Cn) ? W[(size_t)d * Cn + c] : 0.f;
      tile[d][cIdx] = f32_to_bf16(v);
    }
    __syncthreads();
    const int cl = tid >> 2, dq = tid & 3;
    if (c0 + cl < Cn) {
      bf16x8 o0, o1;
#pragma unroll
      for (int k = 0; k < 8; ++k) o0[k] = (short)tile[dq * 16 + k][cl];
#pragma unroll
      for (int k = 0; k < 8; ++k) o1[k] = (short)tile[dq * 16 + 8 + k][cl];
      unsigned short* dst = Wt + (size_t)(c0 + cl) * 64 + dq * 16;
      *reinterpret_cast<bf16x8*>(dst)     = o0;
      *reinterpret_cast<bf16x8*>(dst + 8) = o1;
    }
  } else {
    const int i = ((b - NBLK_W) * 256 + tid) * 4;
    if (i < Bn * Dn) {
      const float4 v = *reinterpret_cast<const float4*>(x + i);
      ushort4 o;
      o.x = f32_to_bf16(v.x * LOG2E); o.y = f32_to_bf16(v.y * LOG2E);
      o.z = f32_to_bf16(v.z * LOG2E); o.w = f32_to_bf16(v.w * LOG2E);
      *reinterpret_cast<ushort4*>(xb + i) = o;
    }
  }
}

__device__ __forceinline__ void loadChunk(
    const unsigned short* __restrict__ Wt, const float* __restrict__ bias,
    int cb, int lr, int lg, bf16x8 (&b)[2][2], float (&bb)[2])
{
  const unsigned short* p0 = Wt + (size_t)(cb + lr) * 64 + lg * 8;
  const unsigned short* p1 = p0 + 16 * 64;
  b[0][0] = *reinterpret_cast<const bf16x8*>(p0);
  b[0][1] = *reinterpret_cast<const bf16x8*>(p0 + 32);
  b[1][0] = *reinterpret_cast<const bf16x8*>(p1);
  b[1][1] = *reinterpret_cast<const bf16x8*>(p1 + 32);
  bb[0] = bias[cb + lr] * LOG2E;
  bb[1] = bias[cb + 16 + lr] * LOG2E;
}

// A pre-scaled by LOG2E; bias*LOG2E is the MFMA C-init -> exp2 of raw acc
// (zero VALU ops between MFMA and v_exp). Validated rounds 2-3, absmax 0.
__device__ __forceinline__ void computeChunk(
    const bf16x8 (&a)[4][2], const bf16x8 (&b)[2][2], const float (&bb)[2],
    float (&esum)[4][4])
{
  f32x4 acc[4][2];
#pragma unroll
  for (int t = 0; t < 4; ++t) {
    acc[t][0] = f32x4{bb[0], bb[0], bb[0], bb[0]};
    acc[t][1] = f32x4{bb[1], bb[1], bb[1], bb[1]};
  }
#pragma unroll
  for (int t = 0; t < 4; ++t) {
    acc[t][0] = __builtin_amdgcn_mfma_f32_16x16x32_bf16(a[t][0], b[0][0], acc[t][0], 0, 0, 0);
    acc[t][1] = __builtin_amdgcn_mfma_f32_16x16x32_bf16(a[t][0], b[1][0], acc[t][1], 0, 0, 0);
    acc[t][0] = __builtin_amdgcn_mfma_f32_16x16x32_bf16(a[t][1], b[0][1], acc[t][0], 0, 0, 0);
    acc[t][1] = __builtin_amdgcn_mfma_f32_16x16x32_bf16(a[t][1], b[1][1], acc[t][1], 0, 0, 0);
  }
#pragma unroll
  for (int t = 0; t < 4; ++t)
#pragma unroll
    for (int j = 0; j < 4; ++j) {
      const float e0 = __builtin_amdgcn_exp2f(acc[t][0][j]);
      const float e1 = __builtin_amdgcn_exp2f(acc[t][1][j]);
      esum[t][j] += e0 + e1;
    }
}

// GEMM+exp-sum: 2500 blocks x 256. Bijective chunked XCD mapping keeps a
// split's 4 sample-group blocks on one XCD (L2-shared Wt slice).
__global__ __launch_bounds__(256) void gemm_expsum_kernel(
    const unsigned short* __restrict__ xb, const unsigned short* __restrict__ Wt,
    const float* __restrict__ bias, float* __restrict__ P)
{
  const int b   = blockIdx.x;
  const int xcd = b & 7, bs = b >> 3;
  // nwg=2500: xcd 0..3 get 313 blocks, 4..7 get 312 (bijective).
  const int wgid = (xcd < 4 ? xcd * 313 : 1252 + (xcd - 4) * 312) + bs;
  const int split = wgid >> 2, sgrp = wgid & 3;

  const int tid  = threadIdx.x;
  const int lane = tid & 63, wid = tid >> 6;
  const int lr = lane & 15, lg = lane >> 4;
  const int sbase = sgrp * 256 + wid * 64;
  const int cb0   = split * CPS;

  bf16x8 a[4][2];
#pragma unroll
  for (int t = 0; t < 4; ++t) {
    const unsigned short* ap = xb + (size_t)(sbase + t * 16 + lr) * 64 + lg * 8;
    a[t][0] = *reinterpret_cast<const bf16x8*>(ap);
    a[t][1] = *reinterpret_cast<const bf16x8*>(ap + 32);
  }

  float esum[4][4];
#pragma unroll
  for (int t = 0; t < 4; ++t)
#pragma unroll
    for (int j = 0; j < 4; ++j) esum[t][j] = 0.f;

  bf16x8 bX[2][2]; float bbX[2];
  bf16x8 bY[2][2]; float bbY[2];
  loadChunk(Wt, bias, cb0, lr, lg, bX, bbX);
#pragma unroll 1
  for (int ch = 0; ch < NCH; ch += 2) {
    if (ch + 1 < NCH) loadChunk(Wt, bias, cb0 + (ch + 1) * 32, lr, lg, bY, bbY);
    computeChunk(a, bX, bbX, esum);
    if (ch + 1 < NCH) {
      if (ch + 2 < NCH) loadChunk(Wt, bias, cb0 + (ch + 2) * 32, lr, lg, bX, bbX);
      computeChunk(a, bY, bbY, esum);
    }
  }

  // Reduce over the 16 lr-lanes (classes), once.
  float red[4][4];
#pragma unroll
  for (int t = 0; t < 4; ++t)
#pragma unroll
    for (int j = 0; j < 4; ++j) {
      float v = esum[t][j];
      v += __shfl_xor(v, 1, 64);
      v += __shfl_xor(v, 2, 64);
      v += __shfl_xor(v, 4, 64);
      v += __shfl_xor(v, 8, 64);
      red[t][j] = v;
    }
  if (lr == 0) {
#pragma unroll
    for (int t = 0; t < 4; ++t)
#pragma unroll
      for (int j = 0; j < 4; ++j)
        P[(size_t)(sbase + t * 16 + lg * 4 + j) * SPLITS + split] = red[t][j];
  }
}

// Loss: reduce P over splits (row-major [sample][split], coalesced) +
// positives from Wt/xb in the log2 domain (bit-consistent with gemm).
__global__ __launch_bounds__(64) void loss2_kernel(
    const unsigned short* __restrict__ xb, const int* __restrict__ labels,
    const unsigned short* __restrict__ Wt, const float* __restrict__ bias,
    const float* __restrict__ P, float* __restrict__ out)
{
  const int i = blockIdx.x, lane = threadIdx.x;
  float acc = 0.f;
  for (int j = lane; j < SPLITS; j += 64) acc += P[(size_t)i * SPLITS + j];
#pragma unroll
  for (int off = 32; off > 0; off >>= 1) acc += __shfl_xor(acc, off, 64);
  const float Si = acc;

  const float xv = bf16_to_f32(xb[i * Dn + lane]);   // = bf16(x*LOG2E), lane=d
  float l2[Kn];
#pragma unroll
  for (int p = 0; p < Kn; ++p) {
    const int c = labels[i * Kn + p];
    float v = xv * bf16_to_f32(Wt[(size_t)c * 64 + lane]);
#pragma unroll
    for (int off = 32; off > 0; off >>= 1) v += __shfl_xor(v, off, 64);
    l2[p] = v + bias[c] * LOG2E;    // logit * LOG2E
  }
  if (lane == 0) {
    float Psum = 0.f;
#pragma unroll
    for (int p = 0; p < Kn; ++p) Psum += __builtin_amdgcn_exp2f(l2[p]);
    const float neg = Si - Psum;
    float lsum = 0.f;
#pragma unroll
    for (int p = 0; p < Kn; ++p)
      lsum += __logf(__builtin_amdgcn_exp2f(l2[p]) + neg) - l2[p] * LN2;
    atomicAdd(out, lsum * (1.0f / (float)(Bn * Kn)));
  }
}

// ===================== OLD (round-2) FALLBACK PATH =====================
constexpr int NB  = 128;
constexpr int NPB = (Cn + NB - 1) / NB;
constexpr int NPBpad = 784;

__global__ __launch_bounds__(256) void cvt_x_kernel(
    const float* __restrict__ x, unsigned short* __restrict__ xb)
{
  const int i = (blockIdx.x * 256 + threadIdx.x) * 4;
  const float4 v = *reinterpret_cast<const float4*>(x + i);
  ushort4 o;
  o.x = f32_to_bf16(v.x); o.y = f32_to_bf16(v.y);
  o.z = f32_to_bf16(v.z); o.w = f32_to_bf16(v.w);
  *reinterpret_cast<ushort4*>(xb + i) = o;
}

__global__ __launch_bounds__(256) void expsum_mfma_kernel(
    const unsigned short* __restrict__ xb, const float* __restrict__ W,
    const float* __restrict__ bias, float* __restrict__ P,
    float* __restrict__ S, int use_partials)
{
  __shared__ float S_lds[4][Bn];
  const int tid  = threadIdx.x;
  const int lane = tid & 63, wid = tid >> 6;
  const int lg = lane >> 4, lr = lane & 15;
  const int cbase = blockIdx.x * NB + wid * 32;

  for (int i = tid; i < 4 * Bn; i += 256) (&S_lds[0][0])[i] = 0.f;

  bf16x8 bfrag[2][2];
  float  bval[2];
#pragma unroll
  for (int t = 0; t < 2; ++t) {
    const int c  = cbase + t * 16 + lr;
    const bool ok = (c < Cn);
    bval[t] = ok ? bias[c] * LOG2E : -1e38f;
#pragma unroll
    for (int h = 0; h < 2; ++h) {
      bf16x8 bf;
#pragma unroll
      for (int j = 0; j < 8; ++j) {
        const int d = h * 32 + lg * 8 + j;
        const float w = ok ? W[(size_t)d * Cn + c] : 0.f;
        bf[j] = (short)f32_to_bf16(w);
      }
      bfrag[t][h] = bf;
    }
  }
  __syncthreads();

#pragma unroll 1
  for (int ch = 0; ch < Bn / 16; ++ch) {
    const int s = ch * 16 + lr;
    const bf16x8 a0 = *reinterpret_cast<const bf16x8*>(xb + (size_t)s * Dn + lg * 8);
    const bf16x8 a1 = *reinterpret_cast<const bf16x8*>(xb + (size_t)s * Dn + 32 + lg * 8);
    f32x4 acc0 = {0.f, 0.f, 0.f, 0.f};
    f32x4 acc1 = {0.f, 0.f, 0.f, 0.f};
    acc0 = __builtin_amdgcn_mfma_f32_16x16x32_bf16(a0, bfrag[0][0], acc0, 0, 0, 0);
    acc1 = __builtin_amdgcn_mfma_f32_16x16x32_bf16(a0, bfrag[1][0], acc1, 0, 0, 0);
    acc0 = __builtin_amdgcn_mfma_f32_16x16x32_bf16(a1, bfrag[0][1], acc0, 0, 0, 0);
    acc1 = __builtin_amdgcn_mfma_f32_16x16x32_bf16(a1, bfrag[1][1], acc1, 0, 0, 0);

    float v[4];
#pragma unroll
    for (int j = 0; j < 4; ++j) {
      const float e0 = __builtin_amdgcn_exp2f(fmaf(acc0[j], LOG2E, bval[0]));
      const float e1 = __builtin_amdgcn_exp2f(fmaf(acc1[j], LOG2E, bval[1]));
      v[j] = e0 + e1;
    }
#pragma unroll
    for (int j = 0; j < 4; ++j) {
      v[j] += __shfl_xor(v[j], 1, 64);
      v[j] += __shfl_xor(v[j], 2, 64);
      v[j] += __shfl_xor(v[j], 4, 64);
      v[j] += __shfl_xor(v[j], 8, 64);
    }
    if (lr == 0) {
#pragma unroll
      for (int j = 0; j < 4; ++j)
        S_lds[wid][ch * 16 + lg * 4 + j] += v[j];
    }
  }
  __syncthreads();

  if (use_partials) {
    for (int s2 = tid; s2 < Bn; s2 += 256) {
      const float v = S_lds[0][s2] + S_lds[1][s2] + S_lds[2][s2] + S_lds[3][s2];
      P[(size_t)s2 * NPBpad + blockIdx.x] = v;
    }
  } else {
    for (int s2 = tid; s2 < Bn; s2 += 256) {
      const float v = S_lds[0][s2] + S_lds[1][s2] + S_lds[2][s2] + S_lds[3][s2];
      atomicAdd(&S[s2], v);
    }
  }
}

__global__ __launch_bounds__(64) void loss_kernel(
    const float* __restrict__ x, const int* __restrict__ labels,
    const float* __restrict__ W, const float* __restrict__ bias,
    const float* __restrict__ P, const float* __restrict__ S,
    float* __restrict__ out, int use_partials)
{
  const int i    = blockIdx.x;
  const int lane = threadIdx.x;

  float Si;
  if (use_partials) {
    float acc = 0.f;
    for (int j = lane; j < NPB; j += 64) acc += P[(size_t)i * NPBpad + j];
#pragma unroll
    for (int off = 32; off > 0; off >>= 1) acc += __shfl_xor(acc, off, 64);
    Si = acc;
  } else {
    Si = S[i];
  }

  const float xv = x[i * Dn + lane];
  float l[Kn];
#pragma unroll
  for (int p = 0; p < Kn; ++p) {
    const int c = labels[i * Kn + p];
    float v = xv * W[(size_t)lane * Cn + c];
#pragma unroll
    for (int off = 32; off > 0; off >>= 1) v += __shfl_xor(v, off, 64);
    l[p] = v + bias[c];
  }

  if (lane == 0) {
    float Psum = 0.f;
#pragma unroll
    for (int p = 0; p < Kn; ++p) Psum += __expf(l[p]);
    const float neg = Si - Psum;
    float lsum = 0.f;
#pragma unroll
    for (int p = 0; p < Kn; ++p)
      lsum += __logf(__expf(l[p]) + neg) - l[p];
    atomicAdd(out, lsum * (1.0f / (float)(Bn * Kn)));
  }
}

// ===================== launch =====================
extern "C" void kernel_launch(void* const* d_in, const int* in_sizes, int n_in,
                              void* d_out, int out_size, void* d_ws, size_t ws_size,
                              hipStream_t stream) {
  const float* x      = (const float*)d_in[0];
  const int*   labels = (const int*)d_in[1];
  const float* W      = (const float*)d_in[2];
  const float* bias   = (const float*)d_in[3];
  float*       out    = (float*)d_out;
  char*        ws     = (char*)d_ws;

  // Main-path ws layout: xb[128K) | P[2.56M) | Wt[12.8M)
  const size_t off_xb = 0;
  const size_t off_P  = (size_t)Bn * Dn * 2;                 // 131072
  const size_t off_Wt = off_P + (size_t)SPLITS * Bn * 4;     // + 2560000
  const size_t need_new = off_Wt + (size_t)Cn * Dn * 2;      // ~15.5 MB

  if (ws_size >= need_new) {
    unsigned short* xb = (unsigned short*)(ws + off_xb);
    float*          P  = (float*)(ws + off_P);
    unsigned short* Wt = (unsigned short*)(ws + off_Wt);
    const int prep_blocks = NBLK_W + (Bn * Dn) / (256 * 4);  // 1563 + 64
    prep_kernel<<<prep_blocks, 256, 0, stream>>>(x, W, xb, Wt, out);
    gemm_expsum_kernel<<<GRID, 256, 0, stream>>>(xb, Wt, bias, P);
    loss2_kernel<<<Bn, 64, 0, stream>>>(xb, labels, Wt, bias, P, out);
    return;
  }

  // Fallback: round-2 path.
  hipMemsetAsync(out, 0, sizeof(float), stream);
  float*          Sg = (float*)ws;
  unsigned short* xb = (unsigned short*)(ws + 4096);
  float*          Pp = (float*)(ws + 4096 + (size_t)Bn * Dn * 2);
  const size_t need_old = 4096 + (size_t)Bn * Dn * 2 + (size_t)Bn * NPBpad * 4;
  const int use_partials = (ws_size >= need_old) ? 1 : 0;
  if (!use_partials) hipMemsetAsync(Sg, 0, Bn * sizeof(float), stream);

  cvt_x_kernel<<<(Bn * Dn) / (256 * 4), 256, 0, stream>>>(x, xb);
  expsum_mfma_kernel<<<NPB, 256, 0, stream>>>(xb, W, bias, Pp, Sg, use_partials);
  loss_kernel<<<Bn, 64, 0, stream>>>(x, labels, W, bias, Pp, Sg, out, use_partials);
}

// Round 5
// 64.620 us; speedup vs baseline: 1.6631x; 1.0964x over previous
//
#include <hip/hip_runtime.h>

constexpr int Bn = 1024;
constexpr int Dn = 64;
constexpr int Cn = 100000;
constexpr int Kn = 5;
constexpr float LOG2E = 1.44269504088896f;
constexpr float LN2   = 0.69314718055994531f;

typedef float f32x4  __attribute__((ext_vector_type(4)));
typedef short bf16x8 __attribute__((ext_vector_type(8)));

__device__ __forceinline__ unsigned short f32_to_bf16(float f) {
  union { float f; unsigned int u; } v; v.f = f;
  unsigned int r = v.u + 0x7FFFu + ((v.u >> 16) & 1u);  // RNE
  return (unsigned short)(r >> 16);
}
__device__ __forceinline__ float bf16_to_f32(unsigned short u) {
  union { unsigned int i; float f; } v; v.i = ((unsigned int)u) << 16; return v.f;
}

// ===================== MAIN PATH (round-1 decomposition) =====================
// SPLITS=125 / NCH=25: long-lived blocks amortize the cold-start latency
// (SPLITS=625/NCH=5 measured 4x slower: all-prologue blocks, round 4).
constexpr int SPLITS = 125;          // class splits, 800 classes each (exact)
constexpr int CPS    = Cn / SPLITS;  // 800
constexpr int NCH    = CPS / 32;     // 25 chunks of 32 classes
constexpr int GRID   = SPLITS * 4;   // 500 blocks
constexpr int NBLK_W = (Cn + 63) / 64;   // 1563 transpose tiles

// Prep: W[64][C] f32 -> Wt[C][64] bf16 (class-major), x -> bf16(x*LOG2E),
// and zero out. Proven coalesced LDS-tile transpose (round-1).
__global__ __launch_bounds__(256) void prep_kernel(
    const float* __restrict__ x, const float* __restrict__ W,
    unsigned short* __restrict__ xb, unsigned short* __restrict__ Wt,
    float* __restrict__ out)
{
  const int tid = threadIdx.x;
  const int b   = blockIdx.x;
  if (b == 0 && tid == 0) *out = 0.f;   // replaces hipMemsetAsync dispatch
  if (b < NBLK_W) {
    __shared__ unsigned short tile[64][71];   // [d][c]; odd pad
    const int c0   = b * 64;
    const int cIdx = tid & 63, dIdx = tid >> 6;
#pragma unroll
    for (int k = 0; k < 16; ++k) {
      const int d = dIdx * 16 + k;
      const int c = c0 + cIdx;
      const float v = (c < Cn) ? W[(size_t)d * Cn + c] : 0.f;
      tile[d][cIdx] = f32_to_bf16(v);
    }
    __syncthreads();
    const int cl = tid >> 2, dq = tid & 3;
    if (c0 + cl < Cn) {
      bf16x8 o0, o1;
#pragma unroll
      for (int k = 0; k < 8; ++k) o0[k] = (short)tile[dq * 16 + k][cl];
#pragma unroll
      for (int k = 0; k < 8; ++k) o1[k] = (short)tile[dq * 16 + 8 + k][cl];
      unsigned short* dst = Wt + (size_t)(c0 + cl) * 64 + dq * 16;
      *reinterpret_cast<bf16x8*>(dst)     = o0;
      *reinterpret_cast<bf16x8*>(dst + 8) = o1;
    }
  } else {
    const int i = ((b - NBLK_W) * 256 + tid) * 4;
    if (i < Bn * Dn) {
      const float4 v = *reinterpret_cast<const float4*>(x + i);
      ushort4 o;
      o.x = f32_to_bf16(v.x * LOG2E); o.y = f32_to_bf16(v.y * LOG2E);
      o.z = f32_to_bf16(v.z * LOG2E); o.w = f32_to_bf16(v.w * LOG2E);
      *reinterpret_cast<ushort4*>(xb + i) = o;
    }
  }
}

__device__ __forceinline__ void loadChunk(
    const unsigned short* __restrict__ Wt, const float* __restrict__ bias,
    int cb, int lr, int lg, bf16x8 (&b)[2][2], float (&bb)[2])
{
  const unsigned short* p0 = Wt + (size_t)(cb + lr) * 64 + lg * 8;
  const unsigned short* p1 = p0 + 16 * 64;
  b[0][0] = *reinterpret_cast<const bf16x8*>(p0);
  b[0][1] = *reinterpret_cast<const bf16x8*>(p0 + 32);
  b[1][0] = *reinterpret_cast<const bf16x8*>(p1);
  b[1][1] = *reinterpret_cast<const bf16x8*>(p1 + 32);
  bb[0] = bias[cb + lr] * LOG2E;
  bb[1] = bias[cb + 16 + lr] * LOG2E;
}

// A pre-scaled by LOG2E; bias*LOG2E is the MFMA C-init -> exp2 of raw acc
// (zero VALU ops between MFMA and v_exp). Numerics proven rounds 2-4.
__device__ __forceinline__ void computeChunk(
    const bf16x8 (&a)[4][2], const bf16x8 (&b)[2][2], const float (&bb)[2],
    float (&esum)[4][4])
{
  f32x4 acc[4][2];
#pragma unroll
  for (int t = 0; t < 4; ++t) {
    acc[t][0] = f32x4{bb[0], bb[0], bb[0], bb[0]};
    acc[t][1] = f32x4{bb[1], bb[1], bb[1], bb[1]};
  }
#pragma unroll
  for (int t = 0; t < 4; ++t) {
    acc[t][0] = __builtin_amdgcn_mfma_f32_16x16x32_bf16(a[t][0], b[0][0], acc[t][0], 0, 0, 0);
    acc[t][1] = __builtin_amdgcn_mfma_f32_16x16x32_bf16(a[t][0], b[1][0], acc[t][1], 0, 0, 0);
    acc[t][0] = __builtin_amdgcn_mfma_f32_16x16x32_bf16(a[t][1], b[0][1], acc[t][0], 0, 0, 0);
    acc[t][1] = __builtin_amdgcn_mfma_f32_16x16x32_bf16(a[t][1], b[1][1], acc[t][1], 0, 0, 0);
  }
#pragma unroll
  for (int t = 0; t < 4; ++t)
#pragma unroll
    for (int j = 0; j < 4; ++j) {
      const float e0 = __builtin_amdgcn_exp2f(acc[t][0][j]);
      const float e1 = __builtin_amdgcn_exp2f(acc[t][1][j]);
      esum[t][j] += e0 + e1;
    }
}

// GEMM+exp-sum: 500 blocks x 256. Bijective chunked XCD mapping keeps a
// split's 4 sample-group blocks on one XCD (L2-shared 102 KB Wt slice).
__global__ __launch_bounds__(256) void gemm_expsum_kernel(
    const unsigned short* __restrict__ xb, const unsigned short* __restrict__ Wt,
    const float* __restrict__ bias, float* __restrict__ P)
{
  const int b   = blockIdx.x;
  const int xcd = b & 7, bs = b >> 3;
  // nwg=500: q=62, r=4 -> xcd 0..3 own 63 blocks, 4..7 own 62 (bijective).
  const int wgid = (xcd < 4 ? xcd * 63 : 252 + (xcd - 4) * 62) + bs;
  const int split = wgid >> 2, sgrp = wgid & 3;

  const int tid  = threadIdx.x;
  const int lane = tid & 63, wid = tid >> 6;
  const int lr = lane & 15, lg = lane >> 4;
  const int sbase = sgrp * 256 + wid * 64;
  const int cb0   = split * CPS;

  bf16x8 a[4][2];
#pragma unroll
  for (int t = 0; t < 4; ++t) {
    const unsigned short* ap = xb + (size_t)(sbase + t * 16 + lr) * 64 + lg * 8;
    a[t][0] = *reinterpret_cast<const bf16x8*>(ap);
    a[t][1] = *reinterpret_cast<const bf16x8*>(ap + 32);
  }

  float esum[4][4];
#pragma unroll
  for (int t = 0; t < 4; ++t)
#pragma unroll
    for (int j = 0; j < 4; ++j) esum[t][j] = 0.f;

  bf16x8 bX[2][2]; float bbX[2];
  bf16x8 bY[2][2]; float bbY[2];
  loadChunk(Wt, bias, cb0, lr, lg, bX, bbX);
#pragma unroll 1
  for (int ch = 0; ch < NCH; ch += 2) {
    if (ch + 1 < NCH) loadChunk(Wt, bias, cb0 + (ch + 1) * 32, lr, lg, bY, bbY);
    computeChunk(a, bX, bbX, esum);
    if (ch + 1 < NCH) {
      if (ch + 2 < NCH) loadChunk(Wt, bias, cb0 + (ch + 2) * 32, lr, lg, bX, bbX);
      computeChunk(a, bY, bbY, esum);
    }
  }

  // Reduce over the 16 lr-lanes (classes), once.
  float red[4][4];
#pragma unroll
  for (int t = 0; t < 4; ++t)
#pragma unroll
    for (int j = 0; j < 4; ++j) {
      float v = esum[t][j];
      v += __shfl_xor(v, 1, 64);
      v += __shfl_xor(v, 2, 64);
      v += __shfl_xor(v, 4, 64);
      v += __shfl_xor(v, 8, 64);
      red[t][j] = v;
    }
  if (lr == 0) {
#pragma unroll
    for (int t = 0; t < 4; ++t)
#pragma unroll
      for (int j = 0; j < 4; ++j)
        P[(size_t)(sbase + t * 16 + lg * 4 + j) * SPLITS + split] = red[t][j];
  }
}

// Loss: reduce P over splits (row-major [sample][split], coalesced) +
// positives from Wt/xb in the log2 domain (bit-consistent with gemm).
__global__ __launch_bounds__(64) void loss2_kernel(
    const unsigned short* __restrict__ xb, const int* __restrict__ labels,
    const unsigned short* __restrict__ Wt, const float* __restrict__ bias,
    const float* __restrict__ P, float* __restrict__ out)
{
  const int i = blockIdx.x, lane = threadIdx.x;
  float acc = P[(size_t)i * SPLITS + lane];
  if (lane + 64 < SPLITS) acc += P[(size_t)i * SPLITS + lane + 64];
#pragma unroll
  for (int off = 32; off > 0; off >>= 1) acc += __shfl_xor(acc, off, 64);
  const float Si = acc;

  const float xv = bf16_to_f32(xb[i * Dn + lane]);   // = bf16(x*LOG2E), lane=d
  float l2[Kn];
#pragma unroll
  for (int p = 0; p < Kn; ++p) {
    const int c = labels[i * Kn + p];
    float v = xv * bf16_to_f32(Wt[(size_t)c * 64 + lane]);
#pragma unroll
    for (int off = 32; off > 0; off >>= 1) v += __shfl_xor(v, off, 64);
    l2[p] = v + bias[c] * LOG2E;    // logit * LOG2E
  }
  if (lane == 0) {
    float Psum = 0.f;
#pragma unroll
    for (int p = 0; p < Kn; ++p) Psum += __builtin_amdgcn_exp2f(l2[p]);
    const float neg = Si - Psum;
    float lsum = 0.f;
#pragma unroll
    for (int p = 0; p < Kn; ++p)
      lsum += __logf(__builtin_amdgcn_exp2f(l2[p]) + neg) - l2[p] * LN2;
    atomicAdd(out, lsum * (1.0f / (float)(Bn * Kn)));
  }
}

// ===================== OLD (round-2) FALLBACK PATH =====================
constexpr int NB  = 128;
constexpr int NPB = (Cn + NB - 1) / NB;
constexpr int NPBpad = 784;

__global__ __launch_bounds__(256) void cvt_x_kernel(
    const float* __restrict__ x, unsigned short* __restrict__ xb)
{
  const int i = (blockIdx.x * 256 + threadIdx.x) * 4;
  const float4 v = *reinterpret_cast<const float4*>(x + i);
  ushort4 o;
  o.x = f32_to_bf16(v.x); o.y = f32_to_bf16(v.y);
  o.z = f32_to_bf16(v.z); o.w = f32_to_bf16(v.w);
  *reinterpret_cast<ushort4*>(xb + i) = o;
}

__global__ __launch_bounds__(256) void expsum_mfma_kernel(
    const unsigned short* __restrict__ xb, const float* __restrict__ W,
    const float* __restrict__ bias, float* __restrict__ P,
    float* __restrict__ S, int use_partials)
{
  __shared__ float S_lds[4][Bn];
  const int tid  = threadIdx.x;
  const int lane = tid & 63, wid = tid >> 6;
  const int lg = lane >> 4, lr = lane & 15;
  const int cbase = blockIdx.x * NB + wid * 32;

  for (int i = tid; i < 4 * Bn; i += 256) (&S_lds[0][0])[i] = 0.f;

  bf16x8 bfrag[2][2];
  float  bval[2];
#pragma unroll
  for (int t = 0; t < 2; ++t) {
    const int c  = cbase + t * 16 + lr;
    const bool ok = (c < Cn);
    bval[t] = ok ? bias[c] * LOG2E : -1e38f;
#pragma unroll
    for (int h = 0; h < 2; ++h) {
      bf16x8 bf;
#pragma unroll
      for (int j = 0; j < 8; ++j) {
        const int d = h * 32 + lg * 8 + j;
        const float w = ok ? W[(size_t)d * Cn + c] : 0.f;
        bf[j] = (short)f32_to_bf16(w);
      }
      bfrag[t][h] = bf;
    }
  }
  __syncthreads();

#pragma unroll 1
  for (int ch = 0; ch < Bn / 16; ++ch) {
    const int s = ch * 16 + lr;
    const bf16x8 a0 = *reinterpret_cast<const bf16x8*>(xb + (size_t)s * Dn + lg * 8);
    const bf16x8 a1 = *reinterpret_cast<const bf16x8*>(xb + (size_t)s * Dn + 32 + lg * 8);
    f32x4 acc0 = {0.f, 0.f, 0.f, 0.f};
    f32x4 acc1 = {0.f, 0.f, 0.f, 0.f};
    acc0 = __builtin_amdgcn_mfma_f32_16x16x32_bf16(a0, bfrag[0][0], acc0, 0, 0, 0);
    acc1 = __builtin_amdgcn_mfma_f32_16x16x32_bf16(a0, bfrag[1][0], acc1, 0, 0, 0);
    acc0 = __builtin_amdgcn_mfma_f32_16x16x32_bf16(a1, bfrag[0][1], acc0, 0, 0, 0);
    acc1 = __builtin_amdgcn_mfma_f32_16x16x32_bf16(a1, bfrag[1][1], acc1, 0, 0, 0);

    float v[4];
#pragma unroll
    for (int j = 0; j < 4; ++j) {
      const float e0 = __builtin_amdgcn_exp2f(fmaf(acc0[j], LOG2E, bval[0]));
      const float e1 = __builtin_amdgcn_exp2f(fmaf(acc1[j], LOG2E, bval[1]));
      v[j] = e0 + e1;
    }
#pragma unroll
    for (int j = 0; j < 4; ++j) {
      v[j] += __shfl_xor(v[j], 1, 64);
      v[j] += __shfl_xor(v[j], 2, 64);
      v[j] += __shfl_xor(v[j], 4, 64);
      v[j] += __shfl_xor(v[j], 8, 64);
    }
    if (lr == 0) {
#pragma unroll
      for (int j = 0; j < 4; ++j)
        S_lds[wid][ch * 16 + lg * 4 + j] += v[j];
    }
  }
  __syncthreads();

  if (use_partials) {
    for (int s2 = tid; s2 < Bn; s2 += 256) {
      const float v = S_lds[0][s2] + S_lds[1][s2] + S_lds[2][s2] + S_lds[3][s2];
      P[(size_t)s2 * NPBpad + blockIdx.x] = v;
    }
  } else {
    for (int s2 = tid; s2 < Bn; s2 += 256) {
      const float v = S_lds[0][s2] + S_lds[1][s2] + S_lds[2][s2] + S_lds[3][s2];
      atomicAdd(&S[s2], v);
    }
  }
}

__global__ __launch_bounds__(64) void loss_kernel(
    const float* __restrict__ x, const int* __restrict__ labels,
    const float* __restrict__ W, const float* __restrict__ bias,
    const float* __restrict__ P, const float* __restrict__ S,
    float* __restrict__ out, int use_partials)
{
  const int i    = blockIdx.x;
  const int lane = threadIdx.x;

  float Si;
  if (use_partials) {
    float acc = 0.f;
    for (int j = lane; j < NPB; j += 64) acc += P[(size_t)i * NPBpad + j];
#pragma unroll
    for (int off = 32; off > 0; off >>= 1) acc += __shfl_xor(acc, off, 64);
    Si = acc;
  } else {
    Si = S[i];
  }

  const float xv = x[i * Dn + lane];
  float l[Kn];
#pragma unroll
  for (int p = 0; p < Kn; ++p) {
    const int c = labels[i * Kn + p];
    float v = xv * W[(size_t)lane * Cn + c];
#pragma unroll
    for (int off = 32; off > 0; off >>= 1) v += __shfl_xor(v, off, 64);
    l[p] = v + bias[c];
  }

  if (lane == 0) {
    float Psum = 0.f;
#pragma unroll
    for (int p = 0; p < Kn; ++p) Psum += __expf(l[p]);
    const float neg = Si - Psum;
    float lsum = 0.f;
#pragma unroll
    for (int p = 0; p < Kn; ++p)
      lsum += __logf(__expf(l[p]) + neg) - l[p];
    atomicAdd(out, lsum * (1.0f / (float)(Bn * Kn)));
  }
}

// ===================== launch =====================
extern "C" void kernel_launch(void* const* d_in, const int* in_sizes, int n_in,
                              void* d_out, int out_size, void* d_ws, size_t ws_size,
                              hipStream_t stream) {
  const float* x      = (const float*)d_in[0];
  const int*   labels = (const int*)d_in[1];
  const float* W      = (const float*)d_in[2];
  const float* bias   = (const float*)d_in[3];
  float*       out    = (float*)d_out;
  char*        ws     = (char*)d_ws;

  // Main-path ws layout: xb[128K) | P[500K) | Wt[12.8M)
  const size_t off_xb = 0;
  const size_t off_P  = (size_t)Bn * Dn * 2;                 // 131072
  const size_t off_Wt = off_P + (size_t)SPLITS * Bn * 4;     // 643072
  const size_t need_new = off_Wt + (size_t)Cn * Dn * 2;      // 13443072

  if (ws_size >= need_new) {
    unsigned short* xb = (unsigned short*)(ws + off_xb);
    float*          P  = (float*)(ws + off_P);
    unsigned short* Wt = (unsigned short*)(ws + off_Wt);
    const int prep_blocks = NBLK_W + (Bn * Dn) / (256 * 4);  // 1563 + 64
    prep_kernel<<<prep_blocks, 256, 0, stream>>>(x, W, xb, Wt, out);
    gemm_expsum_kernel<<<GRID, 256, 0, stream>>>(xb, Wt, bias, P);
    loss2_kernel<<<Bn, 64, 0, stream>>>(xb, labels, Wt, bias, P, out);
    return;
  }

  // Fallback: round-2 path.
  hipMemsetAsync(out, 0, sizeof(float), stream);
  float*          Sg = (float*)ws;
  unsigned short* xb = (unsigned short*)(ws + 4096);
  float*          Pp = (float*)(ws + 4096 + (size_t)Bn * Dn * 2);
  const size_t need_old = 4096 + (size_t)Bn * Dn * 2 + (size_t)Bn * NPBpad * 4;
  const int use_partials = (ws_size >= need_old) ? 1 : 0;
  if (!use_partials) hipMemsetAsync(Sg, 0, Bn * sizeof(float), stream);

  cvt_x_kernel<<<(Bn * Dn) / (256 * 4), 256, 0, stream>>>(x, xb);
  expsum_mfma_kernel<<<NPB, 256, 0, stream>>>(xb, W, bias, Pp, Sg, use_partials);
  loss_kernel<<<Bn, 64, 0, stream>>>(x, labels, W, bias, Pp, Sg, out, use_partials);
}

// Round 6
// 52.513 us; speedup vs baseline: 2.0465x; 1.2306x over previous
//
#include <hip/hip_runtime.h>

constexpr int Bn = 1024;
constexpr int Dn = 64;
constexpr int Cn = 100000;
constexpr int Kn = 5;
constexpr float LOG2E = 1.44269504088896f;
constexpr float LN2   = 0.69314718055994531f;

typedef float f32x4  __attribute__((ext_vector_type(4)));
typedef short bf16x8 __attribute__((ext_vector_type(8)));

__device__ __forceinline__ unsigned short f32_to_bf16(float f) {
  union { float f; unsigned int u; } v; v.f = f;
  unsigned int r = v.u + 0x7FFFu + ((v.u >> 16) & 1u);  // RNE
  return (unsigned short)(r >> 16);
}
__device__ __forceinline__ float bf16_to_f32(unsigned short u) {
  union { unsigned int i; float f; } v; v.i = ((unsigned int)u) << 16; return v.f;
}

// ===================== FUSED MAIN PATH =====================
// SPLITS=125/NCH=25 (proven block length). SGRPS=8 -> 1000 blocks = ~4
// blocks/CU = 4 waves/SIMD (round-5 ran at 2). W is staged per-chunk from
// f32 directly: coalesced float4 row-segments -> double-buffered LDS tile,
// ONE barrier/chunk, no global Wt, no prep kernel.
constexpr int SPLITS = 125;
constexpr int CPS    = Cn / SPLITS;   // 800
constexpr int NCH    = CPS / 32;      // 25 chunks of 32 classes
constexpr int SGRPS  = 8;             // 128 samples per block, 32 per wave
constexpr int GRID   = SPLITS * SGRPS; // 1000
constexpr int TP     = 88;            // LDS tile stride (shorts): 176B, 16B-aligned,
                                      // frag ds_read_b128 -> 2-way banks (free)

__global__ __launch_bounds__(256) void fused_gemm_kernel(
    const float* __restrict__ x, const float* __restrict__ W,
    const float* __restrict__ bias, float* __restrict__ P,
    float* __restrict__ out)
{
  __shared__ unsigned short wt[2][32][TP];   // [buf][class][d], 11.3 KB

  const int b   = blockIdx.x;
  const int tid = threadIdx.x;
  if (b == 0 && tid == 0) *out = 0.f;   // replaces memset dispatch

  // Bijective chunked XCD map (nwg=1000 = 8*125): a split's 8 sample-group
  // blocks land on one XCD -> its 204.8KB W slice is HBM-fetched once.
  const int xcd = b & 7, bs = b >> 3;
  const int wgid  = xcd * 125 + bs;
  const int split = wgid >> 3, sgrp = wgid & 7;

  const int lane = tid & 63, wid = tid >> 6;
  const int lr = lane & 15, lg = lane >> 4;
  const int sbase = sgrp * 128 + wid * 32;
  const int cb0   = split * CPS;

  // ---- A-frags: 32 samples/wave, f32 x -> bf16(x*LOG2E) in registers.
  bf16x8 a[2][2];
#pragma unroll
  for (int t = 0; t < 2; ++t) {
    const float* xp = x + (size_t)(sbase + t * 16 + lr) * 64 + lg * 8;
    const float4 v0 = *reinterpret_cast<const float4*>(xp);
    const float4 v1 = *reinterpret_cast<const float4*>(xp + 4);
    const float4 v2 = *reinterpret_cast<const float4*>(xp + 32);
    const float4 v3 = *reinterpret_cast<const float4*>(xp + 36);
    bf16x8 a0, a1;
    a0[0] = (short)f32_to_bf16(v0.x * LOG2E);
    a0[1] = (short)f32_to_bf16(v0.y * LOG2E);
    a0[2] = (short)f32_to_bf16(v0.z * LOG2E);
    a0[3] = (short)f32_to_bf16(v0.w * LOG2E);
    a0[4] = (short)f32_to_bf16(v1.x * LOG2E);
    a0[5] = (short)f32_to_bf16(v1.y * LOG2E);
    a0[6] = (short)f32_to_bf16(v1.z * LOG2E);
    a0[7] = (short)f32_to_bf16(v1.w * LOG2E);
    a1[0] = (short)f32_to_bf16(v2.x * LOG2E);
    a1[1] = (short)f32_to_bf16(v2.y * LOG2E);
    a1[2] = (short)f32_to_bf16(v2.z * LOG2E);
    a1[3] = (short)f32_to_bf16(v2.w * LOG2E);
    a1[4] = (short)f32_to_bf16(v3.x * LOG2E);
    a1[5] = (short)f32_to_bf16(v3.y * LOG2E);
    a1[6] = (short)f32_to_bf16(v3.z * LOG2E);
    a1[7] = (short)f32_to_bf16(v3.w * LOG2E);
    a[t][0] = a0;
    a[t][1] = a1;
  }

  // Staging roles: thread t loads float4 of W rows sd and sd+32 at classes
  // [sc, sc+4). One inst = 8 rows x 128B contiguous segments (aligned).
  const int sd = tid >> 3;          // 0..31
  const int sc = (tid & 7) * 4;     // 0..28
  const float* wrow0 = W + (size_t)sd * Cn;
  const float* wrow1 = W + (size_t)(sd + 32) * Cn;

  // ---- Stage chunk 0.
  {
    const float4 v0 = *reinterpret_cast<const float4*>(wrow0 + cb0 + sc);
    const float4 v1 = *reinterpret_cast<const float4*>(wrow1 + cb0 + sc);
#pragma unroll
    for (int j = 0; j < 4; ++j) {
      wt[0][sc + j][sd]      = f32_to_bf16(v0[j]);
      wt[0][sc + j][sd + 32] = f32_to_bf16(v1[j]);
    }
  }
  __syncthreads();

  float esum[2][4];
#pragma unroll
  for (int t = 0; t < 2; ++t)
#pragma unroll
    for (int j = 0; j < 4; ++j) esum[t][j] = 0.f;

  // ---- Main loop: prefetch next chunk (global->reg) BEFORE compute so the
  // latency hides under MFMA+exp; regs->LDS after compute; 1 barrier/chunk.
#pragma unroll 1
  for (int ch = 0; ch < NCH; ++ch) {
    float4 n0, n1;
    const bool more = (ch + 1 < NCH);
    if (more) {
      const int cbn = cb0 + (ch + 1) * 32;
      n0 = *reinterpret_cast<const float4*>(wrow0 + cbn + sc);
      n1 = *reinterpret_cast<const float4*>(wrow1 + cbn + sc);
    }

    const int cur = ch & 1;
    const int cb  = cb0 + ch * 32;
    const float bb0 = bias[cb + lr] * LOG2E;
    const float bb1 = bias[cb + 16 + lr] * LOG2E;
    const bf16x8 b00 = *reinterpret_cast<const bf16x8*>(&wt[cur][lr][lg * 8]);
    const bf16x8 b01 = *reinterpret_cast<const bf16x8*>(&wt[cur][lr][32 + lg * 8]);
    const bf16x8 b10 = *reinterpret_cast<const bf16x8*>(&wt[cur][16 + lr][lg * 8]);
    const bf16x8 b11 = *reinterpret_cast<const bf16x8*>(&wt[cur][16 + lr][32 + lg * 8]);

#pragma unroll
    for (int t = 0; t < 2; ++t) {
      f32x4 acc0 = {bb0, bb0, bb0, bb0};
      f32x4 acc1 = {bb1, bb1, bb1, bb1};
      acc0 = __builtin_amdgcn_mfma_f32_16x16x32_bf16(a[t][0], b00, acc0, 0, 0, 0);
      acc1 = __builtin_amdgcn_mfma_f32_16x16x32_bf16(a[t][0], b10, acc1, 0, 0, 0);
      acc0 = __builtin_amdgcn_mfma_f32_16x16x32_bf16(a[t][1], b01, acc0, 0, 0, 0);
      acc1 = __builtin_amdgcn_mfma_f32_16x16x32_bf16(a[t][1], b11, acc1, 0, 0, 0);
#pragma unroll
      for (int j = 0; j < 4; ++j) {
        const float e0 = __builtin_amdgcn_exp2f(acc0[j]);
        const float e1 = __builtin_amdgcn_exp2f(acc1[j]);
        esum[t][j] += e0 + e1;
      }
    }

    if (more) {
      const int nb = (ch + 1) & 1;
#pragma unroll
      for (int j = 0; j < 4; ++j) {
        wt[nb][sc + j][sd]      = f32_to_bf16(n0[j]);
        wt[nb][sc + j][sd + 32] = f32_to_bf16(n1[j]);
      }
    }
    __syncthreads();
  }

  // ---- Reduce over the 16 lr-lanes (classes), once; P[sample][split].
  float red[2][4];
#pragma unroll
  for (int t = 0; t < 2; ++t)
#pragma unroll
    for (int j = 0; j < 4; ++j) {
      float v = esum[t][j];
      v += __shfl_xor(v, 1, 64);
      v += __shfl_xor(v, 2, 64);
      v += __shfl_xor(v, 4, 64);
      v += __shfl_xor(v, 8, 64);
      red[t][j] = v;
    }
  if (lr == 0) {
#pragma unroll
    for (int t = 0; t < 2; ++t)
#pragma unroll
      for (int j = 0; j < 4; ++j)
        P[(size_t)(sbase + t * 16 + lg * 4 + j) * SPLITS + split] = red[t][j];
  }
}

// Loss: P reduce (coalesced) + positives recomputed from f32 W/x with the
// SAME bf16 rounding expressions as the gemm (log2 domain).
__global__ __launch_bounds__(64) void loss3_kernel(
    const float* __restrict__ x, const int* __restrict__ labels,
    const float* __restrict__ W, const float* __restrict__ bias,
    const float* __restrict__ P, float* __restrict__ out)
{
  const int i = blockIdx.x, lane = threadIdx.x;
  float acc = P[(size_t)i * SPLITS + lane];
  if (lane + 64 < SPLITS) acc += P[(size_t)i * SPLITS + lane + 64];
#pragma unroll
  for (int off = 32; off > 0; off >>= 1) acc += __shfl_xor(acc, off, 64);
  const float Si = acc;

  const float xv = bf16_to_f32(f32_to_bf16(x[i * Dn + lane] * LOG2E));  // == A-frag
  float l2[Kn];
#pragma unroll
  for (int p = 0; p < Kn; ++p) {
    const int c = labels[i * Kn + p];
    const float wv = bf16_to_f32(f32_to_bf16(W[(size_t)lane * Cn + c]));  // == staged W
    float v = xv * wv;
#pragma unroll
    for (int off = 32; off > 0; off >>= 1) v += __shfl_xor(v, off, 64);
    l2[p] = v + bias[c] * LOG2E;    // logit * LOG2E
  }
  if (lane == 0) {
    float Psum = 0.f;
#pragma unroll
    for (int p = 0; p < Kn; ++p) Psum += __builtin_amdgcn_exp2f(l2[p]);
    const float neg = Si - Psum;
    float lsum = 0.f;
#pragma unroll
    for (int p = 0; p < Kn; ++p)
      lsum += __logf(__builtin_amdgcn_exp2f(l2[p]) + neg) - l2[p] * LN2;
    atomicAdd(out, lsum * (1.0f / (float)(Bn * Kn)));
  }
}

// ===================== OLD (round-2) FALLBACK PATH =====================
constexpr int NB  = 128;
constexpr int NPB = (Cn + NB - 1) / NB;
constexpr int NPBpad = 784;

__global__ __launch_bounds__(256) void cvt_x_kernel(
    const float* __restrict__ x, unsigned short* __restrict__ xb)
{
  const int i = (blockIdx.x * 256 + threadIdx.x) * 4;
  const float4 v = *reinterpret_cast<const float4*>(x + i);
  ushort4 o;
  o.x = f32_to_bf16(v.x); o.y = f32_to_bf16(v.y);
  o.z = f32_to_bf16(v.z); o.w = f32_to_bf16(v.w);
  *reinterpret_cast<ushort4*>(xb + i) = o;
}

__global__ __launch_bounds__(256) void expsum_mfma_kernel(
    const unsigned short* __restrict__ xb, const float* __restrict__ W,
    const float* __restrict__ bias, float* __restrict__ P,
    float* __restrict__ S, int use_partials)
{
  __shared__ float S_lds[4][Bn];
  const int tid  = threadIdx.x;
  const int lane = tid & 63, wid = tid >> 6;
  const int lg = lane >> 4, lr = lane & 15;
  const int cbase = blockIdx.x * NB + wid * 32;

  for (int i = tid; i < 4 * Bn; i += 256) (&S_lds[0][0])[i] = 0.f;

  bf16x8 bfrag[2][2];
  float  bval[2];
#pragma unroll
  for (int t = 0; t < 2; ++t) {
    const int c  = cbase + t * 16 + lr;
    const bool ok = (c < Cn);
    bval[t] = ok ? bias[c] * LOG2E : -1e38f;
#pragma unroll
    for (int h = 0; h < 2; ++h) {
      bf16x8 bf;
#pragma unroll
      for (int j = 0; j < 8; ++j) {
        const int d = h * 32 + lg * 8 + j;
        const float w = ok ? W[(size_t)d * Cn + c] : 0.f;
        bf[j] = (short)f32_to_bf16(w);
      }
      bfrag[t][h] = bf;
    }
  }
  __syncthreads();

#pragma unroll 1
  for (int ch = 0; ch < Bn / 16; ++ch) {
    const int s = ch * 16 + lr;
    const bf16x8 a0 = *reinterpret_cast<const bf16x8*>(xb + (size_t)s * Dn + lg * 8);
    const bf16x8 a1 = *reinterpret_cast<const bf16x8*>(xb + (size_t)s * Dn + 32 + lg * 8);
    f32x4 acc0 = {0.f, 0.f, 0.f, 0.f};
    f32x4 acc1 = {0.f, 0.f, 0.f, 0.f};
    acc0 = __builtin_amdgcn_mfma_f32_16x16x32_bf16(a0, bfrag[0][0], acc0, 0, 0, 0);
    acc1 = __builtin_amdgcn_mfma_f32_16x16x32_bf16(a0, bfrag[1][0], acc1, 0, 0, 0);
    acc0 = __builtin_amdgcn_mfma_f32_16x16x32_bf16(a1, bfrag[0][1], acc0, 0, 0, 0);
    acc1 = __builtin_amdgcn_mfma_f32_16x16x32_bf16(a1, bfrag[1][1], acc1, 0, 0, 0);

    float v[4];
#pragma unroll
    for (int j = 0; j < 4; ++j) {
      const float e0 = __builtin_amdgcn_exp2f(fmaf(acc0[j], LOG2E, bval[0]));
      const float e1 = __builtin_amdgcn_exp2f(fmaf(acc1[j], LOG2E, bval[1]));
      v[j] = e0 + e1;
    }
#pragma unroll
    for (int j = 0; j < 4; ++j) {
      v[j] += __shfl_xor(v[j], 1, 64);
      v[j] += __shfl_xor(v[j], 2, 64);
      v[j] += __shfl_xor(v[j], 4, 64);
      v[j] += __shfl_xor(v[j], 8, 64);
    }
    if (lr == 0) {
#pragma unroll
      for (int j = 0; j < 4; ++j)
        S_lds[wid][ch * 16 + lg * 4 + j] += v[j];
    }
  }
  __syncthreads();

  if (use_partials) {
    for (int s2 = tid; s2 < Bn; s2 += 256) {
      const float v = S_lds[0][s2] + S_lds[1][s2] + S_lds[2][s2] + S_lds[3][s2];
      P[(size_t)s2 * NPBpad + blockIdx.x] = v;
    }
  } else {
    for (int s2 = tid; s2 < Bn; s2 += 256) {
      const float v = S_lds[0][s2] + S_lds[1][s2] + S_lds[2][s2] + S_lds[3][s2];
      atomicAdd(&S[s2], v);
    }
  }
}

__global__ __launch_bounds__(64) void loss_kernel(
    const float* __restrict__ x, const int* __restrict__ labels,
    const float* __restrict__ W, const float* __restrict__ bias,
    const float* __restrict__ P, const float* __restrict__ S,
    float* __restrict__ out, int use_partials)
{
  const int i    = blockIdx.x;
  const int lane = threadIdx.x;

  float Si;
  if (use_partials) {
    float acc = 0.f;
    for (int j = lane; j < NPB; j += 64) acc += P[(size_t)i * NPBpad + j];
#pragma unroll
    for (int off = 32; off > 0; off >>= 1) acc += __shfl_xor(acc, off, 64);
    Si = acc;
  } else {
    Si = S[i];
  }

  const float xv = x[i * Dn + lane];
  float l[Kn];
#pragma unroll
  for (int p = 0; p < Kn; ++p) {
    const int c = labels[i * Kn + p];
    float v = xv * W[(size_t)lane * Cn + c];
#pragma unroll
    for (int off = 32; off > 0; off >>= 1) v += __shfl_xor(v, off, 64);
    l[p] = v + bias[c];
  }

  if (lane == 0) {
    float Psum = 0.f;
#pragma unroll
    for (int p = 0; p < Kn; ++p) Psum += __expf(l[p]);
    const float neg = Si - Psum;
    float lsum = 0.f;
#pragma unroll
    for (int p = 0; p < Kn; ++p)
      lsum += __logf(__expf(l[p]) + neg) - l[p];
    atomicAdd(out, lsum * (1.0f / (float)(Bn * Kn)));
  }
}

// ===================== launch =====================
extern "C" void kernel_launch(void* const* d_in, const int* in_sizes, int n_in,
                              void* d_out, int out_size, void* d_ws, size_t ws_size,
                              hipStream_t stream) {
  const float* x      = (const float*)d_in[0];
  const int*   labels = (const int*)d_in[1];
  const float* W      = (const float*)d_in[2];
  const float* bias   = (const float*)d_in[3];
  float*       out    = (float*)d_out;
  char*        ws     = (char*)d_ws;

  // Fused-path ws layout: P[512000) only.
  const size_t need_new = (size_t)SPLITS * Bn * 4;   // 512000

  if (ws_size >= need_new) {
    float* P = (float*)ws;
    fused_gemm_kernel<<<GRID, 256, 0, stream>>>(x, W, bias, P, out);
    loss3_kernel<<<Bn, 64, 0, stream>>>(x, labels, W, bias, P, out);
    return;
  }

  // Fallback: round-2 path.
  hipMemsetAsync(out, 0, sizeof(float), stream);
  float*          Sg = (float*)ws;
  unsigned short* xb = (unsigned short*)(ws + 4096);
  float*          Pp = (float*)(ws + 4096 + (size_t)Bn * Dn * 2);
  const size_t need_old = 4096 + (size_t)Bn * Dn * 2 + (size_t)Bn * NPBpad * 4;
  const int use_partials = (ws_size >= need_old) ? 1 : 0;
  if (!use_partials) hipMemsetAsync(Sg, 0, Bn * sizeof(float), stream);

  cvt_x_kernel<<<(Bn * Dn) / (256 * 4), 256, 0, stream>>>(x, xb);
  expsum_mfma_kernel<<<NPB, 256, 0, stream>>>(xb, W, bias, Pp, Sg, use_partials);
  loss_kernel<<<Bn, 64, 0, stream>>>(x, labels, W, bias, Pp, Sg, out, use_partials);
}